// Round 13
// baseline (195.889 us; speedup 1.0000x reference)
//
#include <hip/hip_runtime.h>
#include <hip/hip_bf16.h>

typedef float f32x4 __attribute__((ext_vector_type(4)));
typedef __bf16 bf16x8 __attribute__((ext_vector_type(8)));

#define N_NODES 10000
#define DIM 512
#define MPAD 10112   // 158 * 64
#define DEGCAP 96    // max degree bucket (Poisson(15): P(deg>=96) ~ 1e-40)

// Abuf layout: [8][MPAD][128] bf16. Slices 0-3 = agg quarters, 4-7 = x quarters.
// Each quarter is a CONTIGUOUS 2.59MB block -> spans all L2 channels, fits XCD L2.

// ---------------- zero cnt + queues --------------------------------------------
__global__ __launch_bounds__(256) void zero_kernel(int* __restrict__ cnt) {
    cnt[blockIdx.x * 256 + threadIdx.x] = 0;   // 41 blocks: cnt[10240] + queues[256]
}

// ====== phase1: packw | layernorm -> quarter-major | bucket-fill ===============
__global__ __launch_bounds__(256) void phase1_kernel(
    const float* __restrict__ wl, const float* __restrict__ wr,
    __hip_bfloat16* __restrict__ W,
    const float* __restrict__ xin, const float* __restrict__ gamma,
    const float* __restrict__ beta, __hip_bfloat16* __restrict__ Abuf,
    const int* __restrict__ eidx, int* __restrict__ cnt, int* __restrict__ adj,
    int E, int fill_start) {
    int b = blockIdx.x;
    int tid = threadIdx.x;

    if (b < 512) {
        int idx = b * 256 + tid;
        int base = idx * 4;
        int d = base >> 10;
        int k = base & 1023;
        const float* src = (k < 512) ? (wl + d * 512 + k) : (wr + d * 512 + (k - 512));
        float4 v = *(const float4*)src;
        __hip_bfloat16* o = W + (size_t)d * 1024 + k;
        o[0] = __float2bfloat16(v.x);
        o[1] = __float2bfloat16(v.y);
        o[2] = __float2bfloat16(v.z);
        o[3] = __float2bfloat16(v.w);
    } else if (b < fill_start) {
        int row = (b - 512) * 4 + (tid >> 6);
        int lane = tid & 63;
        const float* xr = xin + (size_t)row * DIM + lane * 8;
        float4 v0 = *(const float4*)xr;
        float4 v1 = *(const float4*)(xr + 4);
        float s  = v0.x + v0.y + v0.z + v0.w + v1.x + v1.y + v1.z + v1.w;
        float ss = v0.x*v0.x + v0.y*v0.y + v0.z*v0.z + v0.w*v0.w
                 + v1.x*v1.x + v1.y*v1.y + v1.z*v1.z + v1.w*v1.w;
        #pragma unroll
        for (int o = 32; o > 0; o >>= 1) {
            s  += __shfl_xor(s, o, 64);
            ss += __shfl_xor(ss, o, 64);
        }
        float mu  = s * (1.0f / 512.0f);
        float var = ss * (1.0f / 512.0f) - mu * mu;
        float rstd = rsqrtf(var + 1e-5f);
        float4 g0 = *(const float4*)(gamma + lane * 8);
        float4 g1 = *(const float4*)(gamma + lane * 8 + 4);
        float4 b0 = *(const float4*)(beta + lane * 8);
        float4 b1 = *(const float4*)(beta + lane * 8 + 4);
        // x quarter slice 4 + (lane>>4), offset (lane&15)*8  == original col lane*8
        __hip_bfloat16* a = Abuf + ((size_t)(4 + (lane >> 4)) * MPAD + row) * 128 + (lane & 15) * 8;
        a[0] = __float2bfloat16((v0.x - mu) * rstd * g0.x + b0.x);
        a[1] = __float2bfloat16((v0.y - mu) * rstd * g0.y + b0.y);
        a[2] = __float2bfloat16((v0.z - mu) * rstd * g0.z + b0.z);
        a[3] = __float2bfloat16((v0.w - mu) * rstd * g0.w + b0.w);
        a[4] = __float2bfloat16((v1.x - mu) * rstd * g1.x + b1.x);
        a[5] = __float2bfloat16((v1.y - mu) * rstd * g1.y + b1.y);
        a[6] = __float2bfloat16((v1.z - mu) * rstd * g1.z + b1.z);
        a[7] = __float2bfloat16((v1.w - mu) * rstd * g1.w + b1.w);
    } else {
        int i = (b - fill_start) * 256 + tid;
        if (i < E) {
            int dst = eidx[E + i];
            int src = eidx[i];
            int pos = atomicAdd(&cnt[dst], 1);
            if (pos < DEGCAP) adj[dst * DEGCAP + pos] = src;
        }
    }
}

// ---------------- gather: XCD-affine quarter-major + work-stealing -------------
// Quarter q = XCC_ID & 3: contiguous 2.59MB x-slice -> L2-resident, all channels.
__global__ __launch_bounds__(256) void gather_kernel(const int* __restrict__ cnt,
                                                     const int* __restrict__ adj,
                                                     __hip_bfloat16* __restrict__ Abuf,
                                                     int* __restrict__ queues) {
    int xcc;
    asm volatile("s_getreg_b32 %0, hwreg(HW_REG_XCC_ID)" : "=s"(xcc));
    const int q = xcc & 3;
    const int w = threadIdx.x >> 6;
    const int lane = threadIdx.x & 63;
    const __hip_bfloat16* xq = Abuf + (size_t)(4 + q) * MPAD * 128;  // x quarter
    __hip_bfloat16*       aq = Abuf + (size_t)q * MPAD * 128;        // agg quarter
    const char* xb = (const char*)xq + lane * 4;
    __shared__ int chunk_s;

    for (;;) {
        if (threadIdx.x == 0) chunk_s = atomicAdd(&queues[q], 1);
        __syncthreads();
        int chunk = chunk_s;
        __syncthreads();
        if (chunk >= 2500) break;
        int node = chunk * 4 + w;
        int deg = cnt[node];
        const int* al = adj + node * DEGCAP;
        float a0 = 0.f, a1 = 0.f;
        int j = 0;
        for (; j + 8 <= deg; j += 8) {
            int n0 = al[j],   n1 = al[j+1], n2 = al[j+2], n3 = al[j+3];
            int n4 = al[j+4], n5 = al[j+5], n6 = al[j+6], n7 = al[j+7];
            unsigned v0 = *(const unsigned*)(xb + (size_t)n0 * 256);
            unsigned v1 = *(const unsigned*)(xb + (size_t)n1 * 256);
            unsigned v2 = *(const unsigned*)(xb + (size_t)n2 * 256);
            unsigned v3 = *(const unsigned*)(xb + (size_t)n3 * 256);
            unsigned v4 = *(const unsigned*)(xb + (size_t)n4 * 256);
            unsigned v5 = *(const unsigned*)(xb + (size_t)n5 * 256);
            unsigned v6 = *(const unsigned*)(xb + (size_t)n6 * 256);
            unsigned v7 = *(const unsigned*)(xb + (size_t)n7 * 256);
            a0 += __uint_as_float(v0 << 16) + __uint_as_float(v1 << 16)
                + __uint_as_float(v2 << 16) + __uint_as_float(v3 << 16)
                + __uint_as_float(v4 << 16) + __uint_as_float(v5 << 16)
                + __uint_as_float(v6 << 16) + __uint_as_float(v7 << 16);
            a1 += __uint_as_float(v0 & 0xffff0000u) + __uint_as_float(v1 & 0xffff0000u)
                + __uint_as_float(v2 & 0xffff0000u) + __uint_as_float(v3 & 0xffff0000u)
                + __uint_as_float(v4 & 0xffff0000u) + __uint_as_float(v5 & 0xffff0000u)
                + __uint_as_float(v6 & 0xffff0000u) + __uint_as_float(v7 & 0xffff0000u);
        }
        for (; j + 4 <= deg; j += 4) {
            int n0 = al[j], n1 = al[j+1], n2 = al[j+2], n3 = al[j+3];
            unsigned v0 = *(const unsigned*)(xb + (size_t)n0 * 256);
            unsigned v1 = *(const unsigned*)(xb + (size_t)n1 * 256);
            unsigned v2 = *(const unsigned*)(xb + (size_t)n2 * 256);
            unsigned v3 = *(const unsigned*)(xb + (size_t)n3 * 256);
            a0 += __uint_as_float(v0 << 16) + __uint_as_float(v1 << 16)
                + __uint_as_float(v2 << 16) + __uint_as_float(v3 << 16);
            a1 += __uint_as_float(v0 & 0xffff0000u) + __uint_as_float(v1 & 0xffff0000u)
                + __uint_as_float(v2 & 0xffff0000u) + __uint_as_float(v3 & 0xffff0000u);
        }
        for (; j < deg; ++j) {
            unsigned v0 = *(const unsigned*)(xb + (size_t)al[j] * 256);
            a0 += __uint_as_float(v0 << 16);
            a1 += __uint_as_float(v0 & 0xffff0000u);
        }
        float sc = 1.0f / fmaxf((float)deg, 1.0f);
        __hip_bfloat16 h0 = __float2bfloat16(a0 * sc);
        __hip_bfloat16 h1 = __float2bfloat16(a1 * sc);
        unsigned pack = (unsigned)*(unsigned short*)&h0
                      | ((unsigned)*(unsigned short*)&h1 << 16);
        __builtin_nontemporal_store(pack, (unsigned*)((char*)aq + (size_t)node * 256 + lane * 4));
    }
}

// ---------------- GEMM: R9 counted-vmcnt, A read from quarter-major ------------
__global__ __launch_bounds__(256) void gemm_kernel(const __hip_bfloat16* __restrict__ Abuf,
                                                   const __hip_bfloat16* __restrict__ Wb,
                                                   const float* __restrict__ bias,
                                                   const float* __restrict__ resid,
                                                   float* __restrict__ out) {
    __shared__ __hip_bfloat16 As[3][64 * 32];
    __shared__ __hip_bfloat16 Bs[3][64 * 32];
    const int tid = threadIdx.x;
    const int lane = tid & 63;
    const int w = tid >> 6;
    const int wr = w >> 1, wc = w & 1;   // 2x2 waves, wave tile 32x32

    int bid = blockIdx.x;
    int tl = (bid & 7) * 158 + (bid >> 3);   // XCD-chunked bijective swizzle
    int mx = tl >> 3, ny = tl & 7;
    const size_t arow0 = (size_t)mx * 64;
    const size_t bcol0 = (size_t)ny * 64;

    f32x4 acc[2][2] = {};

    const int rsw = ((lane & 15) >> 1) & 3;
    const int csw = (((lane >> 4) ^ rsw) & 3) * 8;

    // K-step t covers k in [t*32, t*32+32) -> quarter slice s = t>>2 (constant
    // per step since 32 | 128); in-quarter offset (t&3)*32 + c8*8. Same bytes,
    // same LDS layout as row-major version -> fragment pairing untouched.
#define STAGE(buf, t)                                                                \
    {                                                                                \
        int r = tid >> 2, sl = tid & 3;                                              \
        int c8 = sl ^ ((r >> 1) & 3);                                                \
        const __hip_bfloat16* ga = Abuf + ((size_t)((t) >> 2) * MPAD + arow0 + r) * 128 \
                                   + ((t) & 3) * 32 + c8 * 8;                        \
        __builtin_amdgcn_global_load_lds(                                            \
            (const __attribute__((address_space(1))) void*)ga,                       \
            (__attribute__((address_space(3))) void*)(As[buf] + tid * 8), 16, 0, 0); \
        const __hip_bfloat16* gb = Wb + (size_t)(bcol0 + r) * 1024 + (t) * 32 + c8 * 8; \
        __builtin_amdgcn_global_load_lds(                                            \
            (const __attribute__((address_space(1))) void*)gb,                       \
            (__attribute__((address_space(3))) void*)(Bs[buf] + tid * 8), 16, 0, 0); \
    }

    STAGE(0, 0)
    STAGE(1, 1)

    #pragma unroll
    for (int t = 0; t < 32; ++t) {
        if (t < 31) { asm volatile("s_waitcnt vmcnt(2)" ::: "memory"); }
        else        { asm volatile("s_waitcnt vmcnt(0)" ::: "memory"); }
        __builtin_amdgcn_s_barrier();
        __builtin_amdgcn_sched_barrier(0);
        if (t + 2 < 32) STAGE((t + 2) % 3, t + 2)

        const int p = t % 3;
        bf16x8 af[2], bfr[2];
        #pragma unroll
        for (int m = 0; m < 2; ++m)
            af[m] = *(const bf16x8*)(As[p] + (wr * 32 + m * 16 + (lane & 15)) * 32 + csw);
        #pragma unroll
        for (int n = 0; n < 2; ++n)
            bfr[n] = *(const bf16x8*)(Bs[p] + (wc * 32 + n * 16 + (lane & 15)) * 32 + csw);
        #pragma unroll
        for (int m = 0; m < 2; ++m)
            #pragma unroll
            for (int n = 0; n < 2; ++n)
                acc[m][n] = __builtin_amdgcn_mfma_f32_16x16x32_bf16(af[m], bfr[n], acc[m][n], 0, 0, 0);
    }
#undef STAGE

    #pragma unroll
    for (int m = 0; m < 2; ++m) {
        int rowb = (int)arow0 + wr * 32 + m * 16 + (lane >> 4) * 4;
        #pragma unroll
        for (int n = 0; n < 2; ++n) {
            int col = (int)bcol0 + wc * 32 + n * 16 + (lane & 15);
            float bv = bias[col];
            #pragma unroll
            for (int j = 0; j < 4; ++j) {
                int row = rowb + j;
                if (row < N_NODES) {
                    float v = acc[m][n][j] + bv;
                    v = v > 0.0f ? v : 0.0f;
                    out[(size_t)row * 512 + col] = v + resid[(size_t)row * 512 + col];
                }
            }
        }
    }
}

extern "C" void kernel_launch(void* const* d_in, const int* in_sizes, int n_in,
                              void* d_out, int out_size, void* d_ws, size_t ws_size,
                              hipStream_t stream) {
    const float* node  = (const float*)d_in[0];
    const int*   eidx  = (const int*)d_in[1];
    const float* gamma = (const float*)d_in[2];
    const float* beta  = (const float*)d_in[3];
    const float* wl    = (const float*)d_in[4];
    const float* bl    = (const float*)d_in[5];
    const float* wr    = (const float*)d_in[6];
    float* out = (float*)d_out;
    const int E = in_sizes[1] / 2;

    char* ws = (char*)d_ws;
    int* cnt    = (int*)ws;                                // [10240]
    int* queues = cnt + 10240;                             // [256] (4 used)
    int* adj    = queues + 256;                            // [N_NODES * DEGCAP]
    size_t adj_bytes = ((size_t)N_NODES * DEGCAP * 4 + 255) & ~(size_t)255;
    __hip_bfloat16* Abuf = (__hip_bfloat16*)((char*)adj + adj_bytes);   // [8][MPAD][128]
    __hip_bfloat16* W = Abuf + (size_t)8 * MPAD * 128;                  // [512][1024]

    const int fill_start = 512 + 2500;
    const int nFill = (E + 255) / 256;

    zero_kernel<<<41, 256, 0, stream>>>(cnt);
    phase1_kernel<<<fill_start + nFill, 256, 0, stream>>>(
        wl, wr, W, node, gamma, beta, Abuf, eidx, cnt, adj, E, fill_start);
    gather_kernel<<<2048, 256, 0, stream>>>(cnt, adj, Abuf, queues);
    gemm_kernel<<<1264, 256, 0, stream>>>(Abuf, W, bl, node, out);
}

// Round 14
// 89.444 us; speedup vs baseline: 2.1901x; 2.1901x over previous
//
#include <hip/hip_runtime.h>
#include <hip/hip_bf16.h>

typedef float f32x4 __attribute__((ext_vector_type(4)));
typedef __bf16 bf16x8 __attribute__((ext_vector_type(8)));

#define N_NODES 10000
#define DIM 512
#define MPAD 10112   // 158 * 64
#define DEGCAP 96    // max degree bucket (Poisson(15): P(deg>=96) ~ 1e-40)

// Abuf layout: [8][MPAD][128] bf16. Slices 0-3 = agg quarters, 4-7 = x quarters.
// Each quarter is a CONTIGUOUS 2.59MB block -> fits one XCD's 4MB L2.

// ---------------- zero cnt + queues --------------------------------------------
__global__ __launch_bounds__(256) void zero_kernel(int* __restrict__ cnt) {
    cnt[blockIdx.x * 256 + threadIdx.x] = 0;   // 41 blocks: cnt[10240] + queues[256]
}

// ====== phase1: packw | layernorm -> quarter-major | bucket-fill (FROZEN) ======
__global__ __launch_bounds__(256) void phase1_kernel(
    const float* __restrict__ wl, const float* __restrict__ wr,
    __hip_bfloat16* __restrict__ W,
    const float* __restrict__ xin, const float* __restrict__ gamma,
    const float* __restrict__ beta, __hip_bfloat16* __restrict__ Abuf,
    const int* __restrict__ eidx, int* __restrict__ cnt, int* __restrict__ adj,
    int E, int fill_start) {
    int b = blockIdx.x;
    int tid = threadIdx.x;

    if (b < 512) {
        int idx = b * 256 + tid;
        int base = idx * 4;
        int d = base >> 10;
        int k = base & 1023;
        const float* src = (k < 512) ? (wl + d * 512 + k) : (wr + d * 512 + (k - 512));
        float4 v = *(const float4*)src;
        __hip_bfloat16* o = W + (size_t)d * 1024 + k;
        o[0] = __float2bfloat16(v.x);
        o[1] = __float2bfloat16(v.y);
        o[2] = __float2bfloat16(v.z);
        o[3] = __float2bfloat16(v.w);
    } else if (b < fill_start) {
        int row = (b - 512) * 4 + (tid >> 6);
        int lane = tid & 63;
        const float* xr = xin + (size_t)row * DIM + lane * 8;
        float4 v0 = *(const float4*)xr;
        float4 v1 = *(const float4*)(xr + 4);
        float s  = v0.x + v0.y + v0.z + v0.w + v1.x + v1.y + v1.z + v1.w;
        float ss = v0.x*v0.x + v0.y*v0.y + v0.z*v0.z + v0.w*v0.w
                 + v1.x*v1.x + v1.y*v1.y + v1.z*v1.z + v1.w*v1.w;
        #pragma unroll
        for (int o = 32; o > 0; o >>= 1) {
            s  += __shfl_xor(s, o, 64);
            ss += __shfl_xor(ss, o, 64);
        }
        float mu  = s * (1.0f / 512.0f);
        float var = ss * (1.0f / 512.0f) - mu * mu;
        float rstd = rsqrtf(var + 1e-5f);
        float4 g0 = *(const float4*)(gamma + lane * 8);
        float4 g1 = *(const float4*)(gamma + lane * 8 + 4);
        float4 b0 = *(const float4*)(beta + lane * 8);
        float4 b1 = *(const float4*)(beta + lane * 8 + 4);
        __hip_bfloat16* a = Abuf + ((size_t)(4 + (lane >> 4)) * MPAD + row) * 128 + (lane & 15) * 8;
        a[0] = __float2bfloat16((v0.x - mu) * rstd * g0.x + b0.x);
        a[1] = __float2bfloat16((v0.y - mu) * rstd * g0.y + b0.y);
        a[2] = __float2bfloat16((v0.z - mu) * rstd * g0.z + b0.z);
        a[3] = __float2bfloat16((v0.w - mu) * rstd * g0.w + b0.w);
        a[4] = __float2bfloat16((v1.x - mu) * rstd * g1.x + b1.x);
        a[5] = __float2bfloat16((v1.y - mu) * rstd * g1.y + b1.y);
        a[6] = __float2bfloat16((v1.z - mu) * rstd * g1.z + b1.z);
        a[7] = __float2bfloat16((v1.w - mu) * rstd * g1.w + b1.w);
    } else {
        int i = (b - fill_start) * 256 + tid;
        if (i < E) {
            int dst = eidx[E + i];
            int src = eidx[i];
            int pos = atomicAdd(&cnt[dst], 1);
            if (pos < DEGCAP) adj[dst * DEGCAP + pos] = src;
        }
    }
}

// ---------------- gather: XCD-affine quarters, padded queues, 16-node chunks ---
// Fix vs R12/R13: queue counters 256B apart (no false sharing) and 625 total
// grabs (16 nodes/chunk) instead of 10000 -> atomic chain off the critical path.
__global__ __launch_bounds__(256) void gather_kernel(const int* __restrict__ cnt,
                                                     const int* __restrict__ adj,
                                                     __hip_bfloat16* __restrict__ Abuf,
                                                     int* __restrict__ queues) {
    int xcc;
    asm volatile("s_getreg_b32 %0, hwreg(HW_REG_XCC_ID)" : "=s"(xcc));
    const int q = xcc & 3;
    const int w = threadIdx.x >> 6;
    const int lane = threadIdx.x & 63;
    const __hip_bfloat16* xq = Abuf + (size_t)(4 + q) * MPAD * 128;  // x quarter
    __hip_bfloat16*       aq = Abuf + (size_t)q * MPAD * 128;        // agg quarter
    const char* xb = (const char*)xq + lane * 4;
    __shared__ int chunk_s;

    for (;;) {
        if (threadIdx.x == 0) chunk_s = atomicAdd(&queues[q * 64], 1);
        __syncthreads();
        int chunk = chunk_s;
        __syncthreads();
        if (chunk >= 625) break;
        #pragma unroll 1
        for (int i = 0; i < 4; ++i) {
            int node = chunk * 16 + w * 4 + i;
            int deg = cnt[node];
            const int* al = adj + node * DEGCAP;
            float a0 = 0.f, a1 = 0.f;
            int j = 0;
            for (; j + 8 <= deg; j += 8) {
                int n0 = al[j],   n1 = al[j+1], n2 = al[j+2], n3 = al[j+3];
                int n4 = al[j+4], n5 = al[j+5], n6 = al[j+6], n7 = al[j+7];
                unsigned v0 = *(const unsigned*)(xb + (size_t)n0 * 256);
                unsigned v1 = *(const unsigned*)(xb + (size_t)n1 * 256);
                unsigned v2 = *(const unsigned*)(xb + (size_t)n2 * 256);
                unsigned v3 = *(const unsigned*)(xb + (size_t)n3 * 256);
                unsigned v4 = *(const unsigned*)(xb + (size_t)n4 * 256);
                unsigned v5 = *(const unsigned*)(xb + (size_t)n5 * 256);
                unsigned v6 = *(const unsigned*)(xb + (size_t)n6 * 256);
                unsigned v7 = *(const unsigned*)(xb + (size_t)n7 * 256);
                a0 += __uint_as_float(v0 << 16) + __uint_as_float(v1 << 16)
                    + __uint_as_float(v2 << 16) + __uint_as_float(v3 << 16)
                    + __uint_as_float(v4 << 16) + __uint_as_float(v5 << 16)
                    + __uint_as_float(v6 << 16) + __uint_as_float(v7 << 16);
                a1 += __uint_as_float(v0 & 0xffff0000u) + __uint_as_float(v1 & 0xffff0000u)
                    + __uint_as_float(v2 & 0xffff0000u) + __uint_as_float(v3 & 0xffff0000u)
                    + __uint_as_float(v4 & 0xffff0000u) + __uint_as_float(v5 & 0xffff0000u)
                    + __uint_as_float(v6 & 0xffff0000u) + __uint_as_float(v7 & 0xffff0000u);
            }
            for (; j + 4 <= deg; j += 4) {
                int n0 = al[j], n1 = al[j+1], n2 = al[j+2], n3 = al[j+3];
                unsigned v0 = *(const unsigned*)(xb + (size_t)n0 * 256);
                unsigned v1 = *(const unsigned*)(xb + (size_t)n1 * 256);
                unsigned v2 = *(const unsigned*)(xb + (size_t)n2 * 256);
                unsigned v3 = *(const unsigned*)(xb + (size_t)n3 * 256);
                a0 += __uint_as_float(v0 << 16) + __uint_as_float(v1 << 16)
                    + __uint_as_float(v2 << 16) + __uint_as_float(v3 << 16);
                a1 += __uint_as_float(v0 & 0xffff0000u) + __uint_as_float(v1 & 0xffff0000u)
                    + __uint_as_float(v2 & 0xffff0000u) + __uint_as_float(v3 & 0xffff0000u);
            }
            for (; j < deg; ++j) {
                unsigned v0 = *(const unsigned*)(xb + (size_t)al[j] * 256);
                a0 += __uint_as_float(v0 << 16);
                a1 += __uint_as_float(v0 & 0xffff0000u);
            }
            float sc = 1.0f / fmaxf((float)deg, 1.0f);
            __hip_bfloat16 h0 = __float2bfloat16(a0 * sc);
            __hip_bfloat16 h1 = __float2bfloat16(a1 * sc);
            unsigned pack = (unsigned)*(unsigned short*)&h0
                          | ((unsigned)*(unsigned short*)&h1 << 16);
            __builtin_nontemporal_store(pack, (unsigned*)((char*)aq + (size_t)node * 256 + lane * 4));
        }
    }
}

// ---------------- GEMM: R9 counted-vmcnt, A read from quarter-major (FROZEN) ---
__global__ __launch_bounds__(256) void gemm_kernel(const __hip_bfloat16* __restrict__ Abuf,
                                                   const __hip_bfloat16* __restrict__ Wb,
                                                   const float* __restrict__ bias,
                                                   const float* __restrict__ resid,
                                                   float* __restrict__ out) {
    __shared__ __hip_bfloat16 As[3][64 * 32];
    __shared__ __hip_bfloat16 Bs[3][64 * 32];
    const int tid = threadIdx.x;
    const int lane = tid & 63;
    const int w = tid >> 6;
    const int wr = w >> 1, wc = w & 1;   // 2x2 waves, wave tile 32x32

    int bid = blockIdx.x;
    int tl = (bid & 7) * 158 + (bid >> 3);   // XCD-chunked bijective swizzle
    int mx = tl >> 3, ny = tl & 7;
    const size_t arow0 = (size_t)mx * 64;
    const size_t bcol0 = (size_t)ny * 64;

    f32x4 acc[2][2] = {};

    const int rsw = ((lane & 15) >> 1) & 3;
    const int csw = (((lane >> 4) ^ rsw) & 3) * 8;

#define STAGE(buf, t)                                                                \
    {                                                                                \
        int r = tid >> 2, sl = tid & 3;                                              \
        int c8 = sl ^ ((r >> 1) & 3);                                                \
        const __hip_bfloat16* ga = Abuf + ((size_t)((t) >> 2) * MPAD + arow0 + r) * 128 \
                                   + ((t) & 3) * 32 + c8 * 8;                        \
        __builtin_amdgcn_global_load_lds(                                            \
            (const __attribute__((address_space(1))) void*)ga,                       \
            (__attribute__((address_space(3))) void*)(As[buf] + tid * 8), 16, 0, 0); \
        const __hip_bfloat16* gb = Wb + (size_t)(bcol0 + r) * 1024 + (t) * 32 + c8 * 8; \
        __builtin_amdgcn_global_load_lds(                                            \
            (const __attribute__((address_space(1))) void*)gb,                       \
            (__attribute__((address_space(3))) void*)(Bs[buf] + tid * 8), 16, 0, 0); \
    }

    STAGE(0, 0)
    STAGE(1, 1)

    #pragma unroll
    for (int t = 0; t < 32; ++t) {
        if (t < 31) { asm volatile("s_waitcnt vmcnt(2)" ::: "memory"); }
        else        { asm volatile("s_waitcnt vmcnt(0)" ::: "memory"); }
        __builtin_amdgcn_s_barrier();
        __builtin_amdgcn_sched_barrier(0);
        if (t + 2 < 32) STAGE((t + 2) % 3, t + 2)

        const int p = t % 3;
        bf16x8 af[2], bfr[2];
        #pragma unroll
        for (int m = 0; m < 2; ++m)
            af[m] = *(const bf16x8*)(As[p] + (wr * 32 + m * 16 + (lane & 15)) * 32 + csw);
        #pragma unroll
        for (int n = 0; n < 2; ++n)
            bfr[n] = *(const bf16x8*)(Bs[p] + (wc * 32 + n * 16 + (lane & 15)) * 32 + csw);
        #pragma unroll
        for (int m = 0; m < 2; ++m)
            #pragma unroll
            for (int n = 0; n < 2; ++n)
                acc[m][n] = __builtin_amdgcn_mfma_f32_16x16x32_bf16(af[m], bfr[n], acc[m][n], 0, 0, 0);
    }
#undef STAGE

    #pragma unroll
    for (int m = 0; m < 2; ++m) {
        int rowb = (int)arow0 + wr * 32 + m * 16 + (lane >> 4) * 4;
        #pragma unroll
        for (int n = 0; n < 2; ++n) {
            int col = (int)bcol0 + wc * 32 + n * 16 + (lane & 15);
            float bv = bias[col];
            #pragma unroll
            for (int j = 0; j < 4; ++j) {
                int row = rowb + j;
                if (row < N_NODES) {
                    float v = acc[m][n][j] + bv;
                    v = v > 0.0f ? v : 0.0f;
                    out[(size_t)row * 512 + col] = v + resid[(size_t)row * 512 + col];
                }
            }
        }
    }
}

extern "C" void kernel_launch(void* const* d_in, const int* in_sizes, int n_in,
                              void* d_out, int out_size, void* d_ws, size_t ws_size,
                              hipStream_t stream) {
    const float* node  = (const float*)d_in[0];
    const int*   eidx  = (const int*)d_in[1];
    const float* gamma = (const float*)d_in[2];
    const float* beta  = (const float*)d_in[3];
    const float* wl    = (const float*)d_in[4];
    const float* bl    = (const float*)d_in[5];
    const float* wr    = (const float*)d_in[6];
    float* out = (float*)d_out;
    const int E = in_sizes[1] / 2;

    char* ws = (char*)d_ws;
    int* cnt    = (int*)ws;                                // [10240]
    int* queues = cnt + 10240;                             // [256], counters at q*64
    int* adj    = queues + 256;                            // [N_NODES * DEGCAP]
    size_t adj_bytes = ((size_t)N_NODES * DEGCAP * 4 + 255) & ~(size_t)255;
    __hip_bfloat16* Abuf = (__hip_bfloat16*)((char*)adj + adj_bytes);   // [8][MPAD][128]
    __hip_bfloat16* W = Abuf + (size_t)8 * MPAD * 128;                  // [512][1024]

    const int fill_start = 512 + 2500;
    const int nFill = (E + 255) / 256;

    zero_kernel<<<41, 256, 0, stream>>>(cnt);
    phase1_kernel<<<fill_start + nFill, 256, 0, stream>>>(
        wl, wr, W, node, gamma, beta, Abuf, eidx, cnt, adj, E, fill_start);
    gather_kernel<<<1024, 256, 0, stream>>>(cnt, adj, Abuf, queues);
    gemm_kernel<<<1264, 256, 0, stream>>>(Abuf, W, bl, node, out);
}